// Round 4
// baseline (572.025 us; speedup 1.0000x reference)
//
#include <hip/hip_runtime.h>

typedef float f32x4 __attribute__((ext_vector_type(4)));
typedef __bf16 bf16x8 __attribute__((ext_vector_type(8)));
typedef unsigned short u16x8 __attribute__((ext_vector_type(8)));
typedef unsigned short u16x4 __attribute__((ext_vector_type(4)));

#define MFMA16x16x32 __builtin_amdgcn_mfma_f32_16x16x32_bf16

__device__ __forceinline__ unsigned short f2bf(float f) {
  union { float f; unsigned u; } v; v.f = f;
  unsigned r = v.u + 0x7fffu + ((v.u >> 16) & 1u);  // RNE
  return (unsigned short)(r >> 16);
}
__device__ __forceinline__ float bf2f(unsigned short b) {
  union { unsigned u; float f; } v; v.u = ((unsigned)b) << 16;
  return v.f;
}
__device__ __forceinline__ bf16x8 ldb8(const unsigned short* p) {
  const u16x8* vp = (const u16x8*)__builtin_assume_aligned((const void*)p, 16);
  return __builtin_bit_cast(bf16x8, *vp);
}

// ---- LDS XOR swizzles (T2): fold row&7 into element-index bits 3..5 (byte bits 4..6).
__device__ __forceinline__ int sw8i(int idx) { return idx ^ (((idx >> 8) & 7) << 3); }
__device__ __forceinline__ int sw7i(int idx) { return idx ^ (((idx >> 7) & 7) << 3); }
__device__ __forceinline__ int sw6i(int idx) { return idx ^ (((idx >> 6) & 7) << 3); }

// A-operand weight fragment loader: PRE -> preconverted bf16 in d_ws, else fp32 + inline cvt
template <bool PRE>
__device__ __forceinline__ bf16x8 ldw(const unsigned short* q, const float* f, int off) {
  if constexpr (PRE) {
    return ldb8(q + off);
  } else {
    u16x8 u;
#pragma unroll
    for (int j = 0; j < 8; ++j) u[j] = f2bf(f[off + j]);
    return __builtin_bit_cast(bf16x8, u);
  }
}

__global__ void cvt_weights(const float* __restrict__ a, const float* __restrict__ b,
                            const float* __restrict__ c, const float* __restrict__ d,
                            unsigned short* __restrict__ o) {
  int i = blockIdx.x * 256 + threadIdx.x;     // 131072 total
  int m = i >> 15, r = i & 32767;
  const float* s = (m == 0) ? a : (m == 1) ? b : (m == 2) ? c : d;
  o[i] = f2bf(s[r]);
}

// One block per window n = c*16 + tb*8 + q.  256 threads = 4 waves.
// Window global layout: 8 chunks (wt=t 0..7) of 8 KB CONTIGUOUS fp32 each (16 h-rows x 128 w),
// chunks 64 KB apart. P1/P5 exploit this: coalesced dwordx4 <-> LDS fp32 scratch transpose.
template <bool PRE>
__global__ __launch_bounds__(256, 2) void nlb(
    const float* __restrict__ x, const unsigned short* __restrict__ wq,
    const float* __restrict__ tw, const float* __restrict__ pw,
    const float* __restrict__ gw, const float* __restrict__ wwp,
    const float* __restrict__ tbv, const float* __restrict__ pbv,
    const float* __restrict__ gbv, const float* __restrict__ wbv,
    float* __restrict__ out) {
  // Single 80 KB LDS arena, manually carved so overlays are well-defined.
  __shared__ __attribute__((aligned(16))) unsigned short SH[40960];
  unsigned short* Xbs = SH;            // [s][cc] bf16, sw8i, 16384 u16 (32 KB)
  unsigned short* Tht = SH + 16384;    // [s][i] sw7i, 8192 u16; At overlays (sw6i)
  unsigned short* Pht = SH + 24576;    // [t][i] sw7i, 8192 u16; Yt overlays (sw7i)
  unsigned short* Gs  = SH + 32768;    // [i][t] sw6i, 8192 u16
  // fp32 scratch (8192 floats = 32 KB) overlays Tht+Pht; live only in P1 and P5 epilogue.
  float* scr = (float*)(SH + 16384);
  f32x4* scr4 = (f32x4*)scr;

  const int tid = threadIdx.x;
  const int n = blockIdx.x;
  const int c = n >> 4;
  const int tb = (n >> 3) & 1;
  const int qq = n & 7;
  const int base = c * 262144 + tb * 131072 + qq * 2048; // x element offset of window

  const int lane = tid & 63;
  const int wv = tid >> 6;   // wave id 0..3
  const int col = lane & 15;
  const int quad = lane >> 4;

  // ---------------- P1: stage X -> Xbs[s][cc] (bf16), coalesced ----------------
  // Chunk = 4 wt values = 8192 floats. Scratch layout: L = wt'*2048 + h_l*128 + w,
  // float4-granule swizzle: granule g4 -> g4 ^ (h_l & 7)  (h_l = (g4>>5)&15).
  {
    f32x4 ra[8], rb[8];
#pragma unroll
    for (int j = 0; j < 8; ++j) {
      const int g4 = j * 256 + tid;          // granule in chunk
      const int wt = g4 >> 9;                // wt' 0..3
      const int off = (g4 * 4) & 2047;       // float offset within 8KB region
      ra[j] = *(const f32x4*)(x + base + wt * 16384 + off);
      rb[j] = *(const f32x4*)(x + base + (4 + wt) * 16384 + off);
    }
    const int wh = lane >> 3, ww = lane & 7;
    const int h1 = wv >> 1;
    const int wbp = wv & 1;
#pragma unroll
    for (int half = 0; half < 2; ++half) {
      // coalesced write of this chunk's registers into swizzled scratch
#pragma unroll
      for (int j = 0; j < 8; ++j) {
        const int g4 = j * 256 + tid;
        const int hl7 = (g4 >> 5) & 7;
        scr4[g4 ^ hl7] = (half == 0) ? ra[j] : rb[j];
      }
      __syncthreads();
      // transpose: build cc-contiguous u16x4 and write to Xbs
#pragma unroll
      for (int g = 0; g < 8; ++g) {
        const int wb = g * 2 + wbp;
        const int rbase = (h1 * 8 + wh) * 128 + wb * 8 + ww;
        u16x4 v;
#pragma unroll
        for (int wt = 0; wt < 4; ++wt)
          v[wt] = f2bf(scr[(wt * 2048 + rbase) ^ (wh << 2)]);
        *(u16x4*)__builtin_assume_aligned(
            (void*)&Xbs[sw8i(lane * 256 + h1 * 128 + wb * 8 + half * 4)], 8) = v;
      }
      __syncthreads();  // scratch reads done (before next chunk's writes / before P2)
    }
  }

  // ---------------- P2: Th, Ph, G projections (M=128, N=64, K=256) ----------------
  {
    f32x4 aT[2][4], aP[2][4], aG[2][4];
#pragma unroll
    for (int a = 0; a < 2; ++a)
#pragma unroll
      for (int b = 0; b < 4; ++b) { aT[a][b] = (f32x4)0.0f; aP[a][b] = (f32x4)0.0f; aG[a][b] = (f32x4)0.0f; }

#pragma unroll
    for (int ks = 0; ks < 8; ++ks) {
      const int k0 = ks * 32 + quad * 8;
      bf16x8 bfr[4];
#pragma unroll
      for (int nt = 0; nt < 4; ++nt)
        bfr[nt] = ldb8(&Xbs[sw8i((nt * 16 + col) * 256 + k0)]);  // B[k=cc][n=s]
#pragma unroll
      for (int mtl = 0; mtl < 2; ++mtl) {
        const int m0 = wv * 32 + mtl * 16;
        const int aoff = (m0 + col) * 256 + k0;            // A[m=i][k=cc]
        bf16x8 at = ldw<PRE>(wq + 0 * 32768, tw, aoff);
        bf16x8 ap = ldw<PRE>(wq + 1 * 32768, pw, aoff);
        bf16x8 ag = ldw<PRE>(wq + 2 * 32768, gw, aoff);
#pragma unroll
        for (int nt = 0; nt < 4; ++nt) {
          aT[mtl][nt] = MFMA16x16x32(at, bfr[nt], aT[mtl][nt], 0, 0, 0);
          aP[mtl][nt] = MFMA16x16x32(ap, bfr[nt], aP[mtl][nt], 0, 0, 0);
          aG[mtl][nt] = MFMA16x16x32(ag, bfr[nt], aG[mtl][nt], 0, 0, 0);
        }
      }
    }
    // epilogue: C row = i = m0+quad*4+r, col = s = nt*16+col
#pragma unroll
    for (int mtl = 0; mtl < 2; ++mtl) {
      const int m0 = wv * 32 + mtl * 16;
#pragma unroll
      for (int r = 0; r < 4; ++r) {
        const int i = m0 + quad * 4 + r;
        const float bt = tbv[i], bp = pbv[i], bg = gbv[i];
#pragma unroll
        for (int nt = 0; nt < 4; ++nt) {
          const int s = nt * 16 + col;
          Tht[sw7i(s * 128 + i)] = f2bf(aT[mtl][nt][r] + bt);
          Pht[sw7i(s * 128 + i)] = f2bf(aP[mtl][nt][r] + bp);
          Gs[sw6i(i * 64 + s)] = f2bf(aG[mtl][nt][r] + bg);
        }
      }
    }
  }
  __syncthreads();

  // ---------------- P3: F = Th^T * Ph (M=64 s, N=64 t, K=128 i) + softmax ----------------
  unsigned short* At = Tht;  // overlay after sync, layout [s][t] stride 64 (sw6i)
  {
    f32x4 accF[4];
#pragma unroll
    for (int b = 0; b < 4; ++b) accF[b] = (f32x4)0.0f;
    const int ms = wv * 16;
#pragma unroll
    for (int ks = 0; ks < 4; ++ks) {
      const int k0 = ks * 32 + quad * 8;
      bf16x8 af = ldb8(&Tht[sw7i((ms + col) * 128 + k0)]);        // A[m=s][k=i]
#pragma unroll
      for (int nt = 0; nt < 4; ++nt) {
        bf16x8 bp = ldb8(&Pht[sw7i((nt * 16 + col) * 128 + k0)]); // B[k=i][n=t]
        accF[nt] = MFMA16x16x32(af, bp, accF[nt], 0, 0, 0);
      }
    }
    __syncthreads();  // all waves done reading Tht/Pht before overlay writes

    // softmax over t (row = s = ms + quad*4 + r); row lives in the 16 lanes of this quad
#pragma unroll
    for (int r = 0; r < 4; ++r) {
      float mx = fmaxf(fmaxf(accF[0][r], accF[1][r]), fmaxf(accF[2][r], accF[3][r]));
      mx = fmaxf(mx, __shfl_xor(mx, 1));
      mx = fmaxf(mx, __shfl_xor(mx, 2));
      mx = fmaxf(mx, __shfl_xor(mx, 4));
      mx = fmaxf(mx, __shfl_xor(mx, 8));
      float e0 = __expf(accF[0][r] - mx);
      float e1 = __expf(accF[1][r] - mx);
      float e2 = __expf(accF[2][r] - mx);
      float e3 = __expf(accF[3][r] - mx);
      float sum = e0 + e1 + e2 + e3;
      sum += __shfl_xor(sum, 1);
      sum += __shfl_xor(sum, 2);
      sum += __shfl_xor(sum, 4);
      sum += __shfl_xor(sum, 8);
      const float inv = 1.0f / sum;
      const int s = ms + quad * 4 + r;
      At[sw6i(s * 64 + 0 * 16 + col)] = f2bf(e0 * inv);
      At[sw6i(s * 64 + 1 * 16 + col)] = f2bf(e1 * inv);
      At[sw6i(s * 64 + 2 * 16 + col)] = f2bf(e2 * inv);
      At[sw6i(s * 64 + 3 * 16 + col)] = f2bf(e3 * inv);
    }
  }
  __syncthreads();

  // ---------------- P4: Y = G * Attn^T (M=128 i, N=64 s, K=64 t) ----------------
  unsigned short* Yt = Pht;  // overlay, layout [s][i] stride 128 (sw7i)
  {
    f32x4 accY[2][4];
#pragma unroll
    for (int a = 0; a < 2; ++a)
#pragma unroll
      for (int b = 0; b < 4; ++b) accY[a][b] = (f32x4)0.0f;
#pragma unroll
    for (int ks = 0; ks < 2; ++ks) {
      const int k0 = ks * 32 + quad * 8;
      bf16x8 bfr[4];
#pragma unroll
      for (int nt = 0; nt < 4; ++nt)
        bfr[nt] = ldb8(&At[sw6i((nt * 16 + col) * 64 + k0)]);     // B[k=t][n=s] = attn[s][t]
#pragma unroll
      for (int mtl = 0; mtl < 2; ++mtl) {
        const int m0 = wv * 32 + mtl * 16;
        bf16x8 ag = ldb8(&Gs[sw6i((m0 + col) * 64 + k0)]);        // A[m=i][k=t]
#pragma unroll
        for (int nt = 0; nt < 4; ++nt)
          accY[mtl][nt] = MFMA16x16x32(ag, bfr[nt], accY[mtl][nt], 0, 0, 0);
      }
    }
#pragma unroll
    for (int mtl = 0; mtl < 2; ++mtl) {
#pragma unroll
      for (int r = 0; r < 4; ++r) {
        const int i = wv * 32 + mtl * 16 + quad * 4 + r;
#pragma unroll
        for (int nt = 0; nt < 4; ++nt) {
          const int s = nt * 16 + col;
          Yt[sw7i(s * 128 + i)] = f2bf(accY[mtl][nt][r]);
        }
      }
    }
  }
  __syncthreads();

  // ---------------- P5: Z = Ww * Y + wb + residual (M=256 o, N=64 s, K=128 i) ----------------
  {
    f32x4 accZ[4][4];
#pragma unroll
    for (int a = 0; a < 4; ++a)
#pragma unroll
      for (int b = 0; b < 4; ++b) accZ[a][b] = (f32x4)0.0f;
#pragma unroll
    for (int ks = 0; ks < 4; ++ks) {
      const int k0 = ks * 32 + quad * 8;
      bf16x8 bfr[4];
#pragma unroll
      for (int nt = 0; nt < 4; ++nt)
        bfr[nt] = ldb8(&Yt[sw7i((nt * 16 + col) * 128 + k0)]);    // B[k=i][n=s]
#pragma unroll
      for (int mtl = 0; mtl < 4; ++mtl) {
        const int m0 = wv * 64 + mtl * 16;
        bf16x8 aw = ldw<PRE>(wq + 3 * 32768, wwp, (m0 + col) * 128 + k0); // A[m=o][k=i]
#pragma unroll
        for (int nt = 0; nt < 4; ++nt)
          accZ[mtl][nt] = MFMA16x16x32(aw, bfr[nt], accZ[mtl][nt], 0, 0, 0);
      }
    }
    __syncthreads();  // Yt/At/Gs reads done -> scratch region free

    // epilogue: Z + wb[o] + residual -> fp32 scratch (transposed), then coalesced dwordx4 stores.
    // A lane's o has o&4 == (quad&1)*4, so its ENTIRE accZ belongs to chunk (quad&1).
#pragma unroll
    for (int ch = 0; ch < 2; ++ch) {
      if ((quad & 1) == ch) {
#pragma unroll
        for (int mtl = 0; mtl < 4; ++mtl) {
#pragma unroll
          for (int r = 0; r < 4; ++r) {
            const int o = wv * 64 + mtl * 16 + quad * 4 + r;
            const float bo = wbv[o];
            const int h1 = o >> 7, wb = (o >> 3) & 15;   // wt' = r
#pragma unroll
            for (int nt = 0; nt < 4; ++nt) {
              const int s = nt * 16 + col;
              const int wh = s >> 3, ww = s & 7;
              const int hl = h1 * 8 + wh;
              const float v = accZ[mtl][nt][r] + bo + bf2f(Xbs[sw8i(s * 256 + o)]);
              scr[(r * 2048 + hl * 128 + wb * 8 + ww) ^ ((hl & 7) << 2)] = v;
            }
          }
        }
      }
      __syncthreads();
      // coalesced store of this chunk (wt = ch*4 + wt')
#pragma unroll
      for (int j = 0; j < 8; ++j) {
        const int g4 = j * 256 + tid;
        const int wt = g4 >> 9;
        const int off = (g4 * 4) & 2047;
        const int hl7 = (g4 >> 5) & 7;
        *(f32x4*)(out + base + (ch * 4 + wt) * 16384 + off) = scr4[g4 ^ hl7];
      }
      if (ch == 0) __syncthreads();  // scratch reads done before chunk1 overwrites
    }
  }
}

extern "C" void kernel_launch(void* const* d_in, const int* in_sizes, int n_in,
                              void* d_out, int out_size, void* d_ws, size_t ws_size,
                              hipStream_t stream) {
  const float* x = (const float*)d_in[0];
  const float* tw = (const float*)d_in[1];
  const float* tb = (const float*)d_in[2];
  const float* pw = (const float*)d_in[3];
  const float* pb = (const float*)d_in[4];
  const float* gw = (const float*)d_in[5];
  const float* gb = (const float*)d_in[6];
  const float* ww = (const float*)d_in[7];
  const float* wb = (const float*)d_in[8];
  float* out = (float*)d_out;

  const bool pre = ws_size >= (size_t)(131072 * 2);
  if (pre) {
    unsigned short* wq = (unsigned short*)d_ws;
    cvt_weights<<<512, 256, 0, stream>>>(tw, pw, gw, ww, wq);
    nlb<true><<<4096, 256, 0, stream>>>(x, wq, tw, pw, gw, ww, tb, pb, gb, wb, out);
  } else {
    nlb<false><<<4096, 256, 0, stream>>>(x, nullptr, tw, pw, gw, ww, tb, pb, gb, wb, out);
  }
}

// Round 5
// 557.898 us; speedup vs baseline: 1.0253x; 1.0253x over previous
//
#include <hip/hip_runtime.h>

typedef float f32x4 __attribute__((ext_vector_type(4)));
typedef __bf16 bf16x8 __attribute__((ext_vector_type(8)));
typedef unsigned short u16x8 __attribute__((ext_vector_type(8)));
typedef unsigned short u16x4 __attribute__((ext_vector_type(4)));

#define MFMA16x16x32 __builtin_amdgcn_mfma_f32_16x16x32_bf16

__device__ __forceinline__ unsigned short f2bf(float f) {
  __bf16 h = (__bf16)f;                        // native RNE cvt (pairs into v_cvt_pk_bf16_f32)
  return __builtin_bit_cast(unsigned short, h);
}
__device__ __forceinline__ float bf2f(unsigned short b) {
  union { unsigned u; float f; } v; v.u = ((unsigned)b) << 16;
  return v.f;
}
__device__ __forceinline__ bf16x8 ldb8(const unsigned short* p) {
  const u16x8* vp = (const u16x8*)__builtin_assume_aligned((const void*)p, 16);
  return __builtin_bit_cast(bf16x8, *vp);
}
__device__ __forceinline__ u16x4 ldb4(const unsigned short* p) {
  return *(const u16x4*)__builtin_assume_aligned((const void*)p, 8);
}

// ---- LDS XOR swizzles (T2): fold row&7 into element-index bits 3..5 (byte bits 4..6).
__device__ __forceinline__ int sw8i(int idx) { return idx ^ (((idx >> 8) & 7) << 3); }
__device__ __forceinline__ int sw7i(int idx) { return idx ^ (((idx >> 7) & 7) << 3); }
__device__ __forceinline__ int sw6i(int idx) { return idx ^ (((idx >> 6) & 7) << 3); }

// A-operand weight fragment loader: PRE -> preconverted bf16 in d_ws, else fp32 + inline cvt
template <bool PRE>
__device__ __forceinline__ bf16x8 ldw(const unsigned short* q, const float* f, int off) {
  if constexpr (PRE) {
    return ldb8(q + off);
  } else {
    u16x8 u;
#pragma unroll
    for (int j = 0; j < 8; ++j) u[j] = f2bf(f[off + j]);
    return __builtin_bit_cast(bf16x8, u);
  }
}

__global__ void cvt_weights(const float* __restrict__ a, const float* __restrict__ b,
                            const float* __restrict__ c, const float* __restrict__ d,
                            unsigned short* __restrict__ o) {
  int i = blockIdx.x * 256 + threadIdx.x;     // 131072 total
  int m = i >> 15, r = i & 32767;
  const float* s = (m == 0) ? a : (m == 1) ? b : (m == 2) ? c : d;
  o[i] = f2bf(s[r]);
}

// One block per window n = c*16 + tb*8 + q.  256 threads = 4 waves.
// LDS arena 48 KB -> 3 blocks/CU (was 80 KB -> 2): residual held in registers so
// Tht/Pht can OVERLAY Xbs after P2's reads complete.
template <bool PRE>
__global__ __launch_bounds__(256, 3) void nlb(
    const float* __restrict__ x, const unsigned short* __restrict__ wq,
    const float* __restrict__ tw, const float* __restrict__ pw,
    const float* __restrict__ gw, const float* __restrict__ wwp,
    const float* __restrict__ tbv, const float* __restrict__ pbv,
    const float* __restrict__ gbv, const float* __restrict__ wbv,
    float* __restrict__ out) {
  __shared__ __attribute__((aligned(16))) unsigned short SH[24576];  // 48 KB
  unsigned short* Xbs = SH;            // [s][cc] sw8i, 16384 u16 — live P1..P2
  unsigned short* Gs  = SH + 16384;    // [i][t]  sw6i,  8192 u16 — live P2..P4
  unsigned short* Tht = SH;            // [s][i]  sw7i,  8192 u16 — overlays Xbs lo after barrier
  unsigned short* Pht = SH + 8192;     // [t][i]  sw7i,  8192 u16 — overlays Xbs hi; Yt overlays later

  const int tid = threadIdx.x;
  const int n = blockIdx.x;
  const int c = n >> 4;
  const int tb = (n >> 3) & 1;
  const int qq = n & 7;
  const int base = c * 262144 + tb * 131072 + qq * 2048; // x element offset of window

  const int lane = tid & 63;
  const int wv = tid >> 6;   // wave id 0..3
  const int col = lane & 15;
  const int quad = lane >> 4;

  u16x4 res[4][4];  // residual X[o][s] for this thread's P5 outputs (gathered in P2)

  // ---------------- P1: stage X -> Xbs[s][cc] (bf16) ----------------
  {
    const int s = tid & 63;
    const int sub = tid >> 6;
    const int h1 = sub >> 1;
    const int wh = s >> 3, ww = s & 7;
#pragma unroll
    for (int g = 0; g < 8; ++g) {
      const int wb = g * 2 + (sub & 1);
      const float* xp = x + base + h1 * 1024 + wh * 128 + wb * 8 + ww;
      u16x8 v;
#pragma unroll
      for (int wt = 0; wt < 8; ++wt) v[wt] = f2bf(xp[wt * 16384]);
      const int c0 = h1 * 128 + wb * 8;   // + wt packed along vector
      *(u16x8*)__builtin_assume_aligned((void*)&Xbs[sw8i(s * 256 + c0)], 16) = v;
    }
  }
  __syncthreads();

  // ---------------- P2: Th, Ph, G projections (M=128, N=64, K=256) ----------------
  {
    f32x4 aT[2][4], aP[2][4], aG[2][4];
#pragma unroll
    for (int a = 0; a < 2; ++a)
#pragma unroll
      for (int b = 0; b < 4; ++b) { aT[a][b] = (f32x4)0.0f; aP[a][b] = (f32x4)0.0f; aG[a][b] = (f32x4)0.0f; }

#pragma unroll
    for (int ks = 0; ks < 8; ++ks) {
      const int k0 = ks * 32 + quad * 8;
      bf16x8 bfr[4];
#pragma unroll
      for (int nt = 0; nt < 4; ++nt)
        bfr[nt] = ldb8(&Xbs[sw8i((nt * 16 + col) * 256 + k0)]);  // B[k=cc][n=s]
#pragma unroll
      for (int mtl = 0; mtl < 2; ++mtl) {
        const int m0 = wv * 32 + mtl * 16;
        const int aoff = (m0 + col) * 256 + k0;            // A[m=i][k=cc]
        bf16x8 at = ldw<PRE>(wq + 0 * 32768, tw, aoff);
        bf16x8 ap = ldw<PRE>(wq + 1 * 32768, pw, aoff);
        bf16x8 ag = ldw<PRE>(wq + 2 * 32768, gw, aoff);
#pragma unroll
        for (int nt = 0; nt < 4; ++nt) {
          aT[mtl][nt] = MFMA16x16x32(at, bfr[nt], aT[mtl][nt], 0, 0, 0);
          aP[mtl][nt] = MFMA16x16x32(ap, bfr[nt], aP[mtl][nt], 0, 0, 0);
          aG[mtl][nt] = MFMA16x16x32(ag, bfr[nt], aG[mtl][nt], 0, 0, 0);
        }
      }
    }
    // G epilogue straight to Gs (disjoint region from Xbs -> no barrier needed)
#pragma unroll
    for (int mtl = 0; mtl < 2; ++mtl) {
#pragma unroll
      for (int r = 0; r < 4; ++r) {
        const int i = wv * 32 + mtl * 16 + quad * 4 + r;
        const float bg = gbv[i];
#pragma unroll
        for (int nt = 0; nt < 4; ++nt) {
          const int s = nt * 16 + col;
          Gs[sw6i(i * 64 + s)] = f2bf(aG[mtl][nt][r] + bg);
        }
      }
    }
    // residual gather into registers BEFORE Xbs is overlaid (b64: 4 consecutive cc)
#pragma unroll
    for (int mtl = 0; mtl < 4; ++mtl)
#pragma unroll
      for (int nt = 0; nt < 4; ++nt)
        res[mtl][nt] =
            ldb4(&Xbs[sw8i((nt * 16 + col) * 256 + wv * 64 + mtl * 16 + quad * 4)]);
    __syncthreads();  // all waves done reading Xbs -> safe to overlay
    // theta/phi epilogue overlays Xbs region
#pragma unroll
    for (int mtl = 0; mtl < 2; ++mtl) {
#pragma unroll
      for (int r = 0; r < 4; ++r) {
        const int i = wv * 32 + mtl * 16 + quad * 4 + r;
        const float bt = tbv[i], bp = pbv[i];
#pragma unroll
        for (int nt = 0; nt < 4; ++nt) {
          const int s = nt * 16 + col;
          Tht[sw7i(s * 128 + i)] = f2bf(aT[mtl][nt][r] + bt);
          Pht[sw7i(s * 128 + i)] = f2bf(aP[mtl][nt][r] + bp);
        }
      }
    }
  }
  __syncthreads();

  // ---------------- P3: F = Th^T * Ph (M=64 s, N=64 t, K=128 i) + softmax ----------------
  unsigned short* At = Tht;  // overlay after internal barrier, layout [s][t] stride 64 (sw6i)
  {
    f32x4 accF[4];
#pragma unroll
    for (int b = 0; b < 4; ++b) accF[b] = (f32x4)0.0f;
    const int ms = wv * 16;
#pragma unroll
    for (int ks = 0; ks < 4; ++ks) {
      const int k0 = ks * 32 + quad * 8;
      bf16x8 af = ldb8(&Tht[sw7i((ms + col) * 128 + k0)]);        // A[m=s][k=i]
#pragma unroll
      for (int nt = 0; nt < 4; ++nt) {
        bf16x8 bp = ldb8(&Pht[sw7i((nt * 16 + col) * 128 + k0)]); // B[k=i][n=t]
        accF[nt] = MFMA16x16x32(af, bp, accF[nt], 0, 0, 0);
      }
    }
    __syncthreads();  // all waves done reading Tht/Pht before overlay writes

    // softmax over t (row = s = ms + quad*4 + r); row lives in the 16 lanes of this quad
#pragma unroll
    for (int r = 0; r < 4; ++r) {
      float mx = fmaxf(fmaxf(accF[0][r], accF[1][r]), fmaxf(accF[2][r], accF[3][r]));
      mx = fmaxf(mx, __shfl_xor(mx, 1));
      mx = fmaxf(mx, __shfl_xor(mx, 2));
      mx = fmaxf(mx, __shfl_xor(mx, 4));
      mx = fmaxf(mx, __shfl_xor(mx, 8));
      float e0 = __expf(accF[0][r] - mx);
      float e1 = __expf(accF[1][r] - mx);
      float e2 = __expf(accF[2][r] - mx);
      float e3 = __expf(accF[3][r] - mx);
      float sum = e0 + e1 + e2 + e3;
      sum += __shfl_xor(sum, 1);
      sum += __shfl_xor(sum, 2);
      sum += __shfl_xor(sum, 4);
      sum += __shfl_xor(sum, 8);
      const float inv = 1.0f / sum;
      const int s = ms + quad * 4 + r;
      At[sw6i(s * 64 + 0 * 16 + col)] = f2bf(e0 * inv);
      At[sw6i(s * 64 + 1 * 16 + col)] = f2bf(e1 * inv);
      At[sw6i(s * 64 + 2 * 16 + col)] = f2bf(e2 * inv);
      At[sw6i(s * 64 + 3 * 16 + col)] = f2bf(e3 * inv);
    }
  }
  __syncthreads();

  // ---------------- P4: Y = G * Attn^T (M=128 i, N=64 s, K=64 t) ----------------
  unsigned short* Yt = Pht;  // overlay, layout [s][i] stride 128 (sw7i); Pht dead since P3 barrier
  {
    f32x4 accY[2][4];
#pragma unroll
    for (int a = 0; a < 2; ++a)
#pragma unroll
      for (int b = 0; b < 4; ++b) accY[a][b] = (f32x4)0.0f;
#pragma unroll
    for (int ks = 0; ks < 2; ++ks) {
      const int k0 = ks * 32 + quad * 8;
      bf16x8 bfr[4];
#pragma unroll
      for (int nt = 0; nt < 4; ++nt)
        bfr[nt] = ldb8(&At[sw6i((nt * 16 + col) * 64 + k0)]);     // B[k=t][n=s] = attn[s][t]
#pragma unroll
      for (int mtl = 0; mtl < 2; ++mtl) {
        const int m0 = wv * 32 + mtl * 16;
        bf16x8 ag = ldb8(&Gs[sw6i((m0 + col) * 64 + k0)]);        // A[m=i][k=t]
#pragma unroll
        for (int nt = 0; nt < 4; ++nt)
          accY[mtl][nt] = MFMA16x16x32(ag, bfr[nt], accY[mtl][nt], 0, 0, 0);
      }
    }
#pragma unroll
    for (int mtl = 0; mtl < 2; ++mtl) {
#pragma unroll
      for (int r = 0; r < 4; ++r) {
        const int i = wv * 32 + mtl * 16 + quad * 4 + r;
#pragma unroll
        for (int nt = 0; nt < 4; ++nt) {
          const int s = nt * 16 + col;
          Yt[sw7i(s * 128 + i)] = f2bf(accY[mtl][nt][r]);
        }
      }
    }
  }
  __syncthreads();

  // ---------------- P5: Z = Ww * Y + wb + residual (M=256 o, N=64 s, K=128 i) ----------------
  {
    f32x4 accZ[4][4];
#pragma unroll
    for (int a = 0; a < 4; ++a)
#pragma unroll
      for (int b = 0; b < 4; ++b) accZ[a][b] = (f32x4)0.0f;
#pragma unroll
    for (int ks = 0; ks < 4; ++ks) {
      const int k0 = ks * 32 + quad * 8;
      bf16x8 bfr[4];
#pragma unroll
      for (int nt = 0; nt < 4; ++nt)
        bfr[nt] = ldb8(&Yt[sw7i((nt * 16 + col) * 128 + k0)]);    // B[k=i][n=s]
#pragma unroll
      for (int mtl = 0; mtl < 4; ++mtl) {
        const int m0 = wv * 64 + mtl * 16;
        bf16x8 aw = ldw<PRE>(wq + 3 * 32768, wwp, (m0 + col) * 128 + k0); // A[m=o][k=i]
#pragma unroll
        for (int nt = 0; nt < 4; ++nt)
          accZ[mtl][nt] = MFMA16x16x32(aw, bfr[nt], accZ[mtl][nt], 0, 0, 0);
      }
    }
    // epilogue: out(n, cc=o, s) = Z + wb[o] + X[cc=o][s] (residual from registers)
#pragma unroll
    for (int mtl = 0; mtl < 4; ++mtl) {
#pragma unroll
      for (int r = 0; r < 4; ++r) {
        const int o = wv * 64 + mtl * 16 + quad * 4 + r;
        const float bo = wbv[o];
        const int h1 = o >> 7, wb = (o >> 3) & 15, wt = o & 7;
        const int obase = base + wt * 16384 + h1 * 1024 + wb * 8;
#pragma unroll
        for (int nt = 0; nt < 4; ++nt) {
          const int s = nt * 16 + col;
          const int wh = s >> 3, ww = s & 7;
          const float v = accZ[mtl][nt][r] + bo + bf2f(res[mtl][nt][r]);
          out[obase + wh * 128 + ww] = v;
        }
      }
    }
  }
}

extern "C" void kernel_launch(void* const* d_in, const int* in_sizes, int n_in,
                              void* d_out, int out_size, void* d_ws, size_t ws_size,
                              hipStream_t stream) {
  const float* x = (const float*)d_in[0];
  const float* tw = (const float*)d_in[1];
  const float* tb = (const float*)d_in[2];
  const float* pw = (const float*)d_in[3];
  const float* pb = (const float*)d_in[4];
  const float* gw = (const float*)d_in[5];
  const float* gb = (const float*)d_in[6];
  const float* ww = (const float*)d_in[7];
  const float* wb = (const float*)d_in[8];
  float* out = (float*)d_out;

  const bool pre = ws_size >= (size_t)(131072 * 2);
  if (pre) {
    unsigned short* wq = (unsigned short*)d_ws;
    cvt_weights<<<512, 256, 0, stream>>>(tw, pw, gw, ww, wq);
    nlb<true><<<4096, 256, 0, stream>>>(x, wq, tw, pw, gw, ww, tb, pb, gb, wb, out);
  } else {
    nlb<false><<<4096, 256, 0, stream>>>(x, nullptr, tw, pw, gw, ww, tb, pb, gb, wb, out);
  }
}